// Round 4
// baseline (244.561 us; speedup 1.0000x reference)
//
#include <hip/hip_runtime.h>

#define E_    8
#define D_    2048
#define H_    1024
#define T_    2048   // B*L tokens
#define BK    64
#define NN    32     // n-tiles per m-tile (both gemms)

using u16   = unsigned short;
using s16x8 = __attribute__((ext_vector_type(8))) short;
using f32x4 = __attribute__((ext_vector_type(4))) float;

__device__ __forceinline__ u16 f2bf(float f) {
  union { float f; unsigned u; } v; v.f = f;
  unsigned r = v.u + 0x7fffu + ((v.u >> 16) & 1u);   // RNE
  return (u16)(r >> 16);
}
__device__ __forceinline__ s16x8 cvt8(f32x4 a, f32x4 b) {
  s16x8 o;
  o[0]=(short)f2bf(a.x); o[1]=(short)f2bf(a.y); o[2]=(short)f2bf(a.z); o[3]=(short)f2bf(a.w);
  o[4]=(short)f2bf(b.x); o[5]=(short)f2bf(b.y); o[6]=(short)f2bf(b.z); o[7]=(short)f2bf(b.w);
  return o;
}
// swizzled LDS slot (elem index) for (row, 8-elem chunk) in a [*][64] bf16 tile
__device__ __forceinline__ int slot(int r, int c) { return r * 64 + ((c ^ (r & 7)) << 3); }

__device__ __forceinline__ void gload16(const void* g, void* l) {
  __builtin_amdgcn_global_load_lds((const __attribute__((address_space(1))) void*)g,
                                   (__attribute__((address_space(3))) void*)l, 16, 0, 0);
}

// find (e, mt, Ne) for linear m-tile index ml; all static-indexed (registers only)
#define FIND_EXPERT(ml, cnt, e, mt, Ne)                        \
  { int b_ = 0;                                                \
    _Pragma("unroll")                                          \
    for (int i_ = 0; i_ < E_; ++i_) {                          \
      int ti_ = (cnt[i_] + 255) >> 8;                          \
      if ((ml) >= b_ && (ml) < b_ + ti_) {                     \
        e = i_; mt = (ml) - b_; Ne = cnt[i_]; }                \
      b_ += ti_; } }

// ---------------- workspace layout (bytes) ----------------
// xb     : T*D bf16     =  8,388,608  @ 0
// a_buf  : E*T*H bf16   = 33,554,432  @ 8,388,608
// lists  : E*T int      =     65,536  @ 41,943,040
// gates  : T*K f32      =     16,384  @ 42,008,576
// counts : E int        =         32  @ 42,024,960

__global__ __launch_bounds__(256) void init_kernel(
    const float* __restrict__ bias, float* __restrict__ out, int* __restrict__ counts)
{
  int idx = blockIdx.x * 256 + threadIdx.x;          // one float4 of out
  if (blockIdx.x == 0 && threadIdx.x < E_) counts[threadIdx.x] = 0;
  if (idx == 0) out[(size_t)T_ * D_] = 0.0f;         // router aux loss (eval mode)
  int dq = idx & (D_ / 4 - 1);
  f32x4 b = *(const f32x4*)(bias + dq * 4);
  *(f32x4*)(out + (size_t)idx * 4) = b;
}

// one block per token: logits, top-2 + softmax, build expert lists, x -> bf16
__global__ __launch_bounds__(256) void router_kernel(
    const float* __restrict__ x, const float* __restrict__ wg,
    u16* __restrict__ xb, int* __restrict__ lists, float* __restrict__ gates,
    int* __restrict__ counts)
{
  int t = blockIdx.x;
  int tid = threadIdx.x;
  const float* xr = x + (size_t)t * D_;
  float acc[E_];
#pragma unroll
  for (int e = 0; e < E_; ++e) acc[e] = 0.f;
#pragma unroll
  for (int i = 0; i < D_ / 256; ++i) {
    int d = tid + 256 * i;
    float xv = xr[d];
    xb[(size_t)t * D_ + d] = f2bf(xv);
#pragma unroll
    for (int e = 0; e < E_; ++e) acc[e] += xv * wg[e * D_ + d];
  }
#pragma unroll
  for (int off = 32; off >= 1; off >>= 1)
#pragma unroll
    for (int e = 0; e < E_; ++e) acc[e] += __shfl_down(acc[e], off);

  __shared__ float red[4][E_];
  int w = tid >> 6, lane = tid & 63;
  if (lane == 0)
#pragma unroll
    for (int e = 0; e < E_; ++e) red[w][e] = acc[e];
  __syncthreads();
  if (tid == 0) {
    float v0 = -1e30f, v1 = -1e30f; int e0 = 0, e1 = 0;
#pragma unroll
    for (int e = 0; e < E_; ++e) {
      float v = red[0][e] + red[1][e] + red[2][e] + red[3][e];
      if (v > v0)      { v1 = v0; e1 = e0; v0 = v; e0 = e; }
      else if (v > v1) { v1 = v;  e1 = e; }
    }
    float g1 = expf(v1 - v0);
    float inv = 1.f / (1.f + g1);
    float g0 = inv; g1 *= inv;
    int s0 = atomicAdd(&counts[e0], 1);
    lists[e0 * T_ + s0] = t * 2 + 0;
    gates[t * 2 + 0] = g0;
    int s1 = atomicAdd(&counts[e1], 1);
    lists[e1 * T_ + s1] = t * 2 + 1;
    gates[t * 2 + 1] = g1;
  }
}

// grouped GEMM1 + SiLU-GLU. Tile: 256 token-rows x 32 h-cols (64 B-rows: per
// 32-row group, 16 h1-rows then 16 h2-rows). 8 waves (4m x 2n) of 64x32.
// A: gathered bf16 rows via global_load_lds with pre-swizzled source.
// B: w_in fp32 reg-staged -> cvt -> swizzled ds_write. Persistent tile loop.
__global__ __launch_bounds__(512, 4) void gemm1_kernel(
    const u16* __restrict__ xb, const float* __restrict__ w_in,
    const int* __restrict__ lists, const int* __restrict__ counts,
    u16* __restrict__ a_buf)
{
  __shared__ __align__(16) u16 As[2][256 * 64];   // 64 KB
  __shared__ __align__(16) u16 Bs[2][64 * 64];    // 16 KB -> 80 KB total, 2 blocks/CU

  int cnt[E_];
#pragma unroll
  for (int i = 0; i < E_; ++i) cnt[i] = counts[i];
  int mt_total = 0;
#pragma unroll
  for (int i = 0; i < E_; ++i) mt_total += (cnt[i] + 255) >> 8;
  int total = mt_total * NN;

  int tid = threadIdx.x, w = tid >> 6, lane = tid & 63;
  int swzc = ((lane & 7) ^ (lane >> 3)) * 8;      // pre-swizzled source chunk (elems)
  int brow = tid >> 3, bch = tid & 7;             // B staging row / chunk
  int wr = (w >> 1) * 64, wcB = (w & 1) * 32, lrow = lane & 15, g = lane >> 4;
  int lcol = lane & 15, lr4 = (lane >> 4) * 4;

  int bswz = (blockIdx.x & 7) * 64 + (blockIdx.x >> 3);   // XCD-grouped order

  for (int t = bswz; t < total; t += 512) {
    int ml = t >> 5, n = t & (NN - 1);
    int e = 0, mt = 0, Ne = 0;
    FIND_EXPERT(ml, cnt, e, mt, Ne);

    const u16* ap[4];
#pragma unroll
    for (int i = 0; i < 4; ++i) {
      int gr = mt * 256 + 32 * w + 8 * i + (lane >> 3);
      if (gr >= Ne) gr = Ne - 1;
      ap[i] = xb + (size_t)(lists[e * T_ + gr] >> 1) * D_ + swzc;
    }
    // B row brow -> w_in row: per 32-group, [0,16)=h1 [16,32)=h2 of 16 h-cols
    int o = n * 32 + ((brow >> 4) & 1) * H_ + (brow >> 5) * 16 + (brow & 15);
    const float* bp = w_in + (size_t)e * (2 * H_) * D_ + (size_t)o * D_ + bch * 8;

    f32x4 acc[4][2];
#pragma unroll
    for (int m = 0; m < 4; ++m) { acc[m][0] = (f32x4){0,0,0,0}; acc[m][1] = (f32x4){0,0,0,0}; }

    // prologue: stage kt=0 into buf 0
    f32x4 bl0 = *(const f32x4*)(bp), bl1 = *(const f32x4*)(bp + 4);
#pragma unroll
    for (int i = 0; i < 4; ++i) gload16(ap[i], &As[0][(32 * w + 8 * i) * 64]);
    *(s16x8*)(&Bs[0][slot(brow, bch)]) = cvt8(bl0, bl1);
    __syncthreads();

    const int NT = D_ / BK;   // 32
    for (int kt = 0; kt < NT; ++kt) {
      int cur = kt & 1;
      if (kt + 1 < NT) {
        int k = (kt + 1) * BK;
        bl0 = *(const f32x4*)(bp + k); bl1 = *(const f32x4*)(bp + k + 4);
#pragma unroll
        for (int i = 0; i < 4; ++i) gload16(ap[i] + k, &As[cur ^ 1][(32 * w + 8 * i) * 64]);
      }
#pragma unroll
      for (int ks = 0; ks < 2; ++ks) {
        int ch = ks * 4 + g;
        s16x8 af[4], bf[2];
#pragma unroll
        for (int m = 0; m < 4; ++m) af[m] = *(const s16x8*)(&As[cur][slot(wr + m * 16 + lrow, ch)]);
#pragma unroll
        for (int nn = 0; nn < 2; ++nn) bf[nn] = *(const s16x8*)(&Bs[cur][slot(wcB + nn * 16 + lrow, ch)]);
#pragma unroll
        for (int m = 0; m < 4; ++m)
#pragma unroll
          for (int nn = 0; nn < 2; ++nn)
            acc[m][nn] = __builtin_amdgcn_mfma_f32_16x16x32_bf16(af[m], bf[nn], acc[m][nn], 0, 0, 0);
      }
      if (kt + 1 < NT)
        *(s16x8*)(&Bs[cur ^ 1][slot(brow, bch)]) = cvt8(bl0, bl1);  // vmcnt(4): A stays in flight
      __syncthreads();
    }
    // epilogue: a = silu(h1)*h2 -> bf16
#pragma unroll
    for (int m = 0; m < 4; ++m)
#pragma unroll
      for (int q = 0; q < 4; ++q) {
        int row = mt * 256 + wr + m * 16 + lr4 + q;
        if (row < Ne) {
          float h1 = acc[m][0][q], h2 = acc[m][1][q];
          float a = (h1 / (1.f + __expf(-h1))) * h2;
          a_buf[((size_t)e * T_ + row) * H_ + n * 32 + (w & 1) * 16 + lcol] = f2bf(a);
        }
      }
  }
}

// grouped GEMM2: out[t] += gate * (a_row . w_out[e]^T). Tile: 256 rows x 64 d-cols.
__global__ __launch_bounds__(512, 4) void gemm2_kernel(
    const u16* __restrict__ a_buf, const float* __restrict__ w_out,
    const int* __restrict__ lists, const int* __restrict__ counts,
    const float* __restrict__ gates, float* __restrict__ out)
{
  __shared__ __align__(16) u16 As[2][256 * 64];
  __shared__ __align__(16) u16 Bs[2][64 * 64];

  int cnt[E_];
#pragma unroll
  for (int i = 0; i < E_; ++i) cnt[i] = counts[i];
  int mt_total = 0;
#pragma unroll
  for (int i = 0; i < E_; ++i) mt_total += (cnt[i] + 255) >> 8;
  int total = mt_total * NN;

  int tid = threadIdx.x, w = tid >> 6, lane = tid & 63;
  int swzc = ((lane & 7) ^ (lane >> 3)) * 8;
  int brow = tid >> 3, bch = tid & 7;
  int wr = (w >> 1) * 64, wcB = (w & 1) * 32, lrow = lane & 15, g = lane >> 4;
  int lcol = lane & 15, lr4 = (lane >> 4) * 4;

  int bswz = (blockIdx.x & 7) * 64 + (blockIdx.x >> 3);

  for (int t = bswz; t < total; t += 512) {
    int ml = t >> 5, n = t & (NN - 1);
    int e = 0, mt = 0, Ne = 0;
    FIND_EXPERT(ml, cnt, e, mt, Ne);

    const u16* ap[4];
#pragma unroll
    for (int i = 0; i < 4; ++i) {
      int gr = mt * 256 + 32 * w + 8 * i + (lane >> 3);
      if (gr >= Ne) gr = Ne - 1;
      ap[i] = a_buf + ((size_t)e * T_ + gr) * H_ + swzc;
    }
    const float* bp = w_out + (size_t)e * D_ * H_ + (size_t)(n * 64 + brow) * H_ + bch * 8;

    f32x4 acc[4][2];
#pragma unroll
    for (int m = 0; m < 4; ++m) { acc[m][0] = (f32x4){0,0,0,0}; acc[m][1] = (f32x4){0,0,0,0}; }

    f32x4 bl0 = *(const f32x4*)(bp), bl1 = *(const f32x4*)(bp + 4);
#pragma unroll
    for (int i = 0; i < 4; ++i) gload16(ap[i], &As[0][(32 * w + 8 * i) * 64]);
    *(s16x8*)(&Bs[0][slot(brow, bch)]) = cvt8(bl0, bl1);
    __syncthreads();

    const int NT = H_ / BK;   // 16
    for (int kt = 0; kt < NT; ++kt) {
      int cur = kt & 1;
      if (kt + 1 < NT) {
        int k = (kt + 1) * BK;
        bl0 = *(const f32x4*)(bp + k); bl1 = *(const f32x4*)(bp + k + 4);
#pragma unroll
        for (int i = 0; i < 4; ++i) gload16(ap[i] + k, &As[cur ^ 1][(32 * w + 8 * i) * 64]);
      }
#pragma unroll
      for (int ks = 0; ks < 2; ++ks) {
        int ch = ks * 4 + g;
        s16x8 af[4], bf[2];
#pragma unroll
        for (int m = 0; m < 4; ++m) af[m] = *(const s16x8*)(&As[cur][slot(wr + m * 16 + lrow, ch)]);
#pragma unroll
        for (int nn = 0; nn < 2; ++nn) bf[nn] = *(const s16x8*)(&Bs[cur][slot(wcB + nn * 16 + lrow, ch)]);
#pragma unroll
        for (int m = 0; m < 4; ++m)
#pragma unroll
          for (int nn = 0; nn < 2; ++nn)
            acc[m][nn] = __builtin_amdgcn_mfma_f32_16x16x32_bf16(af[m], bf[nn], acc[m][nn], 0, 0, 0);
      }
      if (kt + 1 < NT)
        *(s16x8*)(&Bs[cur ^ 1][slot(brow, bch)]) = cvt8(bl0, bl1);
      __syncthreads();
    }
#pragma unroll
    for (int m = 0; m < 4; ++m)
#pragma unroll
      for (int q = 0; q < 4; ++q) {
        int row = mt * 256 + wr + m * 16 + lr4 + q;
        if (row < Ne) {
          int p = lists[e * T_ + row];
          float gt = gates[p];
          int tok = p >> 1;
#pragma unroll
          for (int nn = 0; nn < 2; ++nn)
            atomicAdd(&out[(size_t)tok * D_ + n * 64 + wcB + nn * 16 + lcol], gt * acc[m][nn][q]);
        }
      }
  }
}

extern "C" void kernel_launch(void* const* d_in, const int* in_sizes, int n_in,
                              void* d_out, int out_size, void* d_ws, size_t ws_size,
                              hipStream_t stream)
{
  const float* x      = (const float*)d_in[0];
  const float* w_gate = (const float*)d_in[1];
  const float* w_in   = (const float*)d_in[2];
  const float* w_out  = (const float*)d_in[3];
  const float* bias   = (const float*)d_in[4];
  float* out = (float*)d_out;

  char* ws = (char*)d_ws;
  u16*   xb     = (u16*)(ws);
  u16*   a_buf  = (u16*)(ws + 8388608);
  int*   lists  = (int*)(ws + 41943040);
  float* gates  = (float*)(ws + 42008576);
  int*   counts = (int*)(ws + 42024960);

  init_kernel<<<T_ * D_ / 4 / 256, 256, 0, stream>>>(bias, out, counts);
  router_kernel<<<T_, 256, 0, stream>>>(x, w_gate, xb, lists, gates, counts);
  gemm1_kernel<<<512, 512, 0, stream>>>(xb, w_in, lists, counts, a_buf);
  gemm2_kernel<<<512, 512, 0, stream>>>(a_buf, w_out, lists, counts, gates, out);
}

// Round 5
// 231.158 us; speedup vs baseline: 1.0580x; 1.0580x over previous
//
#include <hip/hip_runtime.h>

#define E_    8
#define D_    2048
#define H_    1024
#define T_    2048   // B*L tokens
#define BK    64
#define NN    32     // n-tiles per m-tile (both gemms)

using u16   = unsigned short;
using s16x8 = __attribute__((ext_vector_type(8))) short;
using f32x4 = __attribute__((ext_vector_type(4))) float;

__device__ __forceinline__ u16 f2bf(float f) {
  union { float f; unsigned u; } v; v.f = f;
  unsigned r = v.u + 0x7fffu + ((v.u >> 16) & 1u);   // RNE
  return (u16)(r >> 16);
}
__device__ __forceinline__ s16x8 cvt8(f32x4 a, f32x4 b) {
  s16x8 o;
  o[0]=(short)f2bf(a.x); o[1]=(short)f2bf(a.y); o[2]=(short)f2bf(a.z); o[3]=(short)f2bf(a.w);
  o[4]=(short)f2bf(b.x); o[5]=(short)f2bf(b.y); o[6]=(short)f2bf(b.z); o[7]=(short)f2bf(b.w);
  return o;
}
// swizzled LDS slot (elem index) for (row, 8-elem chunk) in a [*][64] bf16 tile
__device__ __forceinline__ int slot(int r, int c) { return r * 64 + ((c ^ (r & 7)) << 3); }

__device__ __forceinline__ void gload16(const void* g, void* l) {
  __builtin_amdgcn_global_load_lds((const __attribute__((address_space(1))) void*)g,
                                   (__attribute__((address_space(3))) void*)l, 16, 0, 0);
}

// find (e, mt, Ne) for linear m-tile index ml; all static-indexed (registers only)
#define FIND_EXPERT(ml, cnt, e, mt, Ne)                        \
  { int b_ = 0;                                                \
    _Pragma("unroll")                                          \
    for (int i_ = 0; i_ < E_; ++i_) {                          \
      int ti_ = (cnt[i_] + 255) >> 8;                          \
      if ((ml) >= b_ && (ml) < b_ + ti_) {                     \
        e = i_; mt = (ml) - b_; Ne = cnt[i_]; }                \
      b_ += ti_; } }

// ---------------- workspace layout (bytes) ----------------
// xb     : T*D bf16     =  8,388,608  @ 0
// a_buf  : E*T*H bf16   = 33,554,432  @ 8,388,608
// lists  : E*T int      =     65,536  @ 41,943,040
// gates  : T*K f32      =     16,384  @ 42,008,576
// counts : E int        =         32  @ 42,024,960

__global__ __launch_bounds__(256) void init_kernel(
    const float* __restrict__ bias, float* __restrict__ out, int* __restrict__ counts)
{
  int idx = blockIdx.x * 256 + threadIdx.x;          // one float4 of out
  if (blockIdx.x == 0 && threadIdx.x < E_) counts[threadIdx.x] = 0;
  if (idx == 0) out[(size_t)T_ * D_] = 0.0f;         // router aux loss (eval mode)
  int dq = idx & (D_ / 4 - 1);
  f32x4 b = *(const f32x4*)(bias + dq * 4);
  *(f32x4*)(out + (size_t)idx * 4) = b;
}

// one block per token: logits, top-2 + softmax, build expert lists, x -> bf16
__global__ __launch_bounds__(256) void router_kernel(
    const float* __restrict__ x, const float* __restrict__ wg,
    u16* __restrict__ xb, int* __restrict__ lists, float* __restrict__ gates,
    int* __restrict__ counts)
{
  int t = blockIdx.x;
  int tid = threadIdx.x;
  const float* xr = x + (size_t)t * D_;
  float acc[E_];
#pragma unroll
  for (int e = 0; e < E_; ++e) acc[e] = 0.f;
#pragma unroll
  for (int i = 0; i < D_ / 256; ++i) {
    int d = tid + 256 * i;
    float xv = xr[d];
    xb[(size_t)t * D_ + d] = f2bf(xv);
#pragma unroll
    for (int e = 0; e < E_; ++e) acc[e] += xv * wg[e * D_ + d];
  }
#pragma unroll
  for (int off = 32; off >= 1; off >>= 1)
#pragma unroll
    for (int e = 0; e < E_; ++e) acc[e] += __shfl_down(acc[e], off);

  __shared__ float red[4][E_];
  int w = tid >> 6, lane = tid & 63;
  if (lane == 0)
#pragma unroll
    for (int e = 0; e < E_; ++e) red[w][e] = acc[e];
  __syncthreads();
  if (tid == 0) {
    float v0 = -1e30f, v1 = -1e30f; int e0 = 0, e1 = 0;
#pragma unroll
    for (int e = 0; e < E_; ++e) {
      float v = red[0][e] + red[1][e] + red[2][e] + red[3][e];
      if (v > v0)      { v1 = v0; e1 = e0; v0 = v; e0 = e; }
      else if (v > v1) { v1 = v;  e1 = e; }
    }
    float g1 = expf(v1 - v0);
    float inv = 1.f / (1.f + g1);
    float g0 = inv; g1 *= inv;
    int s0 = atomicAdd(&counts[e0], 1);
    lists[e0 * T_ + s0] = t * 2 + 0;
    gates[t * 2 + 0] = g0;
    int s1 = atomicAdd(&counts[e1], 1);
    lists[e1 * T_ + s1] = t * 2 + 1;
    gates[t * 2 + 1] = g1;
  }
}

// grouped GEMM1 + SiLU-GLU. Tile: 256 token-rows x 32 h-cols (64 B-rows).
// 8 waves (4m x 2n) of 64x32. Balanced XCD-chunked tile assignment:
// XCD x handles tiles [x*chunk, (x+1)*chunk) via its 64 block-slots.
__global__ __launch_bounds__(512, 4) void gemm1_kernel(
    const u16* __restrict__ xb, const float* __restrict__ w_in,
    const int* __restrict__ lists, const int* __restrict__ counts,
    u16* __restrict__ a_buf)
{
  __shared__ __align__(16) u16 As[2][256 * 64];   // 64 KB
  __shared__ __align__(16) u16 Bs[2][64 * 64];    // 16 KB -> 80 KB total, 2 blocks/CU

  int cnt[E_];
#pragma unroll
  for (int i = 0; i < E_; ++i) cnt[i] = counts[i];
  int mt_total = 0;
#pragma unroll
  for (int i = 0; i < E_; ++i) mt_total += (cnt[i] + 255) >> 8;
  int total = mt_total * NN;
  int chunk = (total + 7) >> 3;                   // tiles per XCD

  int tid = threadIdx.x, w = tid >> 6, lane = tid & 63;
  int swzc = ((lane & 7) ^ (lane >> 3)) * 8;      // pre-swizzled source chunk (elems)
  int brow = tid >> 3, bch = tid & 7;             // B staging row / chunk
  int wr = (w >> 1) * 64, wcB = (w & 1) * 32, lrow = lane & 15, g = lane >> 4;
  int lcol = lane & 15, lr4 = (lane >> 4) * 4;

  int xcd = blockIdx.x & 7, bslot = blockIdx.x >> 3;   // HW: XCD = bid % 8

  for (int sl = bslot; sl < chunk; sl += 64) {
    int t = xcd * chunk + sl;                     // consecutive sl -> same A-panel
    if (t >= total) break;
    int ml = t >> 5, n = t & (NN - 1);
    int e = 0, mt = 0, Ne = 0;
    FIND_EXPERT(ml, cnt, e, mt, Ne);

    const u16* ap[4];
#pragma unroll
    for (int i = 0; i < 4; ++i) {
      int gr = mt * 256 + 32 * w + 8 * i + (lane >> 3);
      if (gr >= Ne) gr = Ne - 1;
      ap[i] = xb + (size_t)(lists[e * T_ + gr] >> 1) * D_ + swzc;
    }
    // B row brow -> w_in row: per 32-group, [0,16)=h1 [16,32)=h2 of 16 h-cols
    int o = n * 32 + ((brow >> 4) & 1) * H_ + (brow >> 5) * 16 + (brow & 15);
    const float* bp = w_in + (size_t)e * (2 * H_) * D_ + (size_t)o * D_ + bch * 8;

    f32x4 acc[4][2];
#pragma unroll
    for (int m = 0; m < 4; ++m) { acc[m][0] = (f32x4){0,0,0,0}; acc[m][1] = (f32x4){0,0,0,0}; }

    // prologue: stage kt=0 into buf 0
    f32x4 bl0 = *(const f32x4*)(bp), bl1 = *(const f32x4*)(bp + 4);
#pragma unroll
    for (int i = 0; i < 4; ++i) gload16(ap[i], &As[0][(32 * w + 8 * i) * 64]);
    *(s16x8*)(&Bs[0][slot(brow, bch)]) = cvt8(bl0, bl1);
    __syncthreads();

    const int NT = D_ / BK;   // 32
    for (int kt = 0; kt < NT; ++kt) {
      int cur = kt & 1;
      if (kt + 1 < NT) {
        int k = (kt + 1) * BK;
        bl0 = *(const f32x4*)(bp + k); bl1 = *(const f32x4*)(bp + k + 4);
#pragma unroll
        for (int i = 0; i < 4; ++i) gload16(ap[i] + k, &As[cur ^ 1][(32 * w + 8 * i) * 64]);
      }
#pragma unroll
      for (int ks = 0; ks < 2; ++ks) {
        int ch = ks * 4 + g;
        s16x8 af[4], bf[2];
#pragma unroll
        for (int m = 0; m < 4; ++m) af[m] = *(const s16x8*)(&As[cur][slot(wr + m * 16 + lrow, ch)]);
#pragma unroll
        for (int nn = 0; nn < 2; ++nn) bf[nn] = *(const s16x8*)(&Bs[cur][slot(wcB + nn * 16 + lrow, ch)]);
#pragma unroll
        for (int m = 0; m < 4; ++m)
#pragma unroll
          for (int nn = 0; nn < 2; ++nn)
            acc[m][nn] = __builtin_amdgcn_mfma_f32_16x16x32_bf16(af[m], bf[nn], acc[m][nn], 0, 0, 0);
      }
      if (kt + 1 < NT)
        *(s16x8*)(&Bs[cur ^ 1][slot(brow, bch)]) = cvt8(bl0, bl1);  // A stays in flight
      __syncthreads();
    }
    // epilogue: a = silu(h1)*h2 -> bf16
#pragma unroll
    for (int m = 0; m < 4; ++m)
#pragma unroll
      for (int q = 0; q < 4; ++q) {
        int row = mt * 256 + wr + m * 16 + lr4 + q;
        if (row < Ne) {
          float h1 = acc[m][0][q], h2 = acc[m][1][q];
          float a = (h1 / (1.f + __expf(-h1))) * h2;
          a_buf[((size_t)e * T_ + row) * H_ + n * 32 + (w & 1) * 16 + lcol] = f2bf(a);
        }
      }
  }
}

// grouped GEMM2: out[t] += gate * (a_row . w_out[e]^T). Tile: 256 rows x 64 d-cols.
__global__ __launch_bounds__(512, 4) void gemm2_kernel(
    const u16* __restrict__ a_buf, const float* __restrict__ w_out,
    const int* __restrict__ lists, const int* __restrict__ counts,
    const float* __restrict__ gates, float* __restrict__ out)
{
  __shared__ __align__(16) u16 As[2][256 * 64];
  __shared__ __align__(16) u16 Bs[2][64 * 64];

  int cnt[E_];
#pragma unroll
  for (int i = 0; i < E_; ++i) cnt[i] = counts[i];
  int mt_total = 0;
#pragma unroll
  for (int i = 0; i < E_; ++i) mt_total += (cnt[i] + 255) >> 8;
  int total = mt_total * NN;
  int chunk = (total + 7) >> 3;

  int tid = threadIdx.x, w = tid >> 6, lane = tid & 63;
  int swzc = ((lane & 7) ^ (lane >> 3)) * 8;
  int brow = tid >> 3, bch = tid & 7;
  int wr = (w >> 1) * 64, wcB = (w & 1) * 32, lrow = lane & 15, g = lane >> 4;
  int lcol = lane & 15, lr4 = (lane >> 4) * 4;

  int xcd = blockIdx.x & 7, bslot = blockIdx.x >> 3;

  for (int sl = bslot; sl < chunk; sl += 64) {
    int t = xcd * chunk + sl;
    if (t >= total) break;
    int ml = t >> 5, n = t & (NN - 1);
    int e = 0, mt = 0, Ne = 0;
    FIND_EXPERT(ml, cnt, e, mt, Ne);

    const u16* ap[4];
#pragma unroll
    for (int i = 0; i < 4; ++i) {
      int gr = mt * 256 + 32 * w + 8 * i + (lane >> 3);
      if (gr >= Ne) gr = Ne - 1;
      ap[i] = a_buf + ((size_t)e * T_ + gr) * H_ + swzc;
    }
    const float* bp = w_out + (size_t)e * D_ * H_ + (size_t)(n * 64 + brow) * H_ + bch * 8;

    f32x4 acc[4][2];
#pragma unroll
    for (int m = 0; m < 4; ++m) { acc[m][0] = (f32x4){0,0,0,0}; acc[m][1] = (f32x4){0,0,0,0}; }

    f32x4 bl0 = *(const f32x4*)(bp), bl1 = *(const f32x4*)(bp + 4);
#pragma unroll
    for (int i = 0; i < 4; ++i) gload16(ap[i], &As[0][(32 * w + 8 * i) * 64]);
    *(s16x8*)(&Bs[0][slot(brow, bch)]) = cvt8(bl0, bl1);
    __syncthreads();

    const int NT = H_ / BK;   // 16
    for (int kt = 0; kt < NT; ++kt) {
      int cur = kt & 1;
      if (kt + 1 < NT) {
        int k = (kt + 1) * BK;
        bl0 = *(const f32x4*)(bp + k); bl1 = *(const f32x4*)(bp + k + 4);
#pragma unroll
        for (int i = 0; i < 4; ++i) gload16(ap[i] + k, &As[cur ^ 1][(32 * w + 8 * i) * 64]);
      }
#pragma unroll
      for (int ks = 0; ks < 2; ++ks) {
        int ch = ks * 4 + g;
        s16x8 af[4], bf[2];
#pragma unroll
        for (int m = 0; m < 4; ++m) af[m] = *(const s16x8*)(&As[cur][slot(wr + m * 16 + lrow, ch)]);
#pragma unroll
        for (int nn = 0; nn < 2; ++nn) bf[nn] = *(const s16x8*)(&Bs[cur][slot(wcB + nn * 16 + lrow, ch)]);
#pragma unroll
        for (int m = 0; m < 4; ++m)
#pragma unroll
          for (int nn = 0; nn < 2; ++nn)
            acc[m][nn] = __builtin_amdgcn_mfma_f32_16x16x32_bf16(af[m], bf[nn], acc[m][nn], 0, 0, 0);
      }
      if (kt + 1 < NT)
        *(s16x8*)(&Bs[cur ^ 1][slot(brow, bch)]) = cvt8(bl0, bl1);
      __syncthreads();
    }
#pragma unroll
    for (int m = 0; m < 4; ++m)
#pragma unroll
      for (int q = 0; q < 4; ++q) {
        int row = mt * 256 + wr + m * 16 + lr4 + q;
        if (row < Ne) {
          int p = lists[e * T_ + row];
          float gt = gates[p];
          int tok = p >> 1;
#pragma unroll
          for (int nn = 0; nn < 2; ++nn)
            atomicAdd(&out[(size_t)tok * D_ + n * 64 + wcB + nn * 16 + lcol], gt * acc[m][nn][q]);
        }
      }
  }
}

extern "C" void kernel_launch(void* const* d_in, const int* in_sizes, int n_in,
                              void* d_out, int out_size, void* d_ws, size_t ws_size,
                              hipStream_t stream)
{
  const float* x      = (const float*)d_in[0];
  const float* w_gate = (const float*)d_in[1];
  const float* w_in   = (const float*)d_in[2];
  const float* w_out  = (const float*)d_in[3];
  const float* bias   = (const float*)d_in[4];
  float* out = (float*)d_out;

  char* ws = (char*)d_ws;
  u16*   xb     = (u16*)(ws);
  u16*   a_buf  = (u16*)(ws + 8388608);
  int*   lists  = (int*)(ws + 41943040);
  float* gates  = (float*)(ws + 42008576);
  int*   counts = (int*)(ws + 42024960);

  init_kernel<<<T_ * D_ / 4 / 256, 256, 0, stream>>>(bias, out, counts);
  router_kernel<<<T_, 256, 0, stream>>>(x, w_gate, xb, lists, gates, counts);
  gemm1_kernel<<<512, 512, 0, stream>>>(xb, w_in, lists, counts, a_buf);
  gemm2_kernel<<<512, 512, 0, stream>>>(a_buf, w_out, lists, counts, gates, out);
}